// Round 5
// baseline (1939.099 us; speedup 1.0000x reference)
//
#include <hip/hip_runtime.h>
#include <hip/hip_bf16.h>

// ---------------------------------------------------------------------------
// Fully-fused persistent BiLSTM + CRF. One kernel does: weight->register prep,
// x (embedding) prep, LSTM recurrence (MFMA, data-flow sync via sentinels),
// feats projection, CRF scan, final reduce. Host: 2 memsets + 1 launch.
constexpr int B_ = 64, S_ = 512, E_ = 300, H_ = 512, T_ = 12;
constexpr int KPADX = 320;          // E padded to 320 (zeros 300..319)
constexpr int KC_TOT = 26;          // (320+512)/32 MFMA k-chunks
constexpr float NEGV = -10000.0f;
constexpr int ASTR = 840;           // LDS A-row stride in shorts (832 + 8)
constexpr unsigned SENT = 0xFFFFFFFFu;  // sentinel dword (bf16 NaN pair)

typedef short bf16x8_t __attribute__((ext_vector_type(8)));
typedef float f32x4_t __attribute__((ext_vector_type(4)));

// ---- workspace layout (bytes) ---------------------------------------------
constexpr size_t XC_OFF = 0;
constexpr size_t XC_BYTES = (size_t)S_ * B_ * KPADX * 2;             // 20,971,520
constexpr size_t HH_OFF = XC_OFF + XC_BYTES;
constexpr size_t HH_BYTES = (size_t)2 * (S_ + 1) * B_ * H_ * 2;      // 67,239,936
constexpr size_t FE_OFF = HH_OFF + HH_BYTES;
constexpr size_t FE_BYTES = (size_t)S_ * B_ * T_ * 4;                // 1,572,864
constexpr size_t LSE_OFF = FE_OFF + FE_BYTES;
constexpr size_t CTR_OFF = LSE_OFF + 256;   // 4 counters, 128 B apart
constexpr size_t CTR_BYTES = 512;

#define AGENT_LD(p)    __hip_atomic_load((p), __ATOMIC_RELAXED, __HIP_MEMORY_SCOPE_AGENT)
#define AGENT_ST(p, v) __hip_atomic_store((p), (v), __ATOMIC_RELAXED, __HIP_MEMORY_SCOPE_AGENT)
#define AGENT_ADD(p)   __hip_atomic_fetch_add((p), 1, __ATOMIC_RELAXED, __HIP_MEMORY_SCOPE_AGENT)

__launch_bounds__(256, 1)
__global__ void bilstm_crf_persist(
    const int* __restrict__ tokens, const int* __restrict__ lengths,
    const float* __restrict__ Wemb,
    const float* __restrict__ Wih_f, const float* __restrict__ Whh_f, const float* __restrict__ b_f,
    const float* __restrict__ Wih_b, const float* __restrict__ Whh_b, const float* __restrict__ b_b,
    const float* __restrict__ h0, const float* __restrict__ c0,
    const float* __restrict__ Wout, const float* __restrict__ bout,
    const float* __restrict__ trans,
    char* __restrict__ ws, float* __restrict__ out) {
  __shared__ __align__(16) char arena[49536];
  short* pool = (short*)arena;                  // [16][ASTR] A-tile (lstm)
  float* gl = (float*)(arena + 16 * ASTR * 2);  // gate exchange (lstm)
  float* wl = (float*)arena;                    // Wout [12][1032] (feats)

  const int bid = blockIdx.x;
  const int dir = bid >> 7, rr = bid & 127, nt = rr >> 2, mt = rr & 3;
  const int tid = threadIdx.x, lane = tid & 63, wv = tid >> 6;
  const int quad = lane >> 4, l16 = lane & 15;
  __hip_bfloat16* xc = (__hip_bfloat16*)(ws + XC_OFF);
  __hip_bfloat16* hh = (__hip_bfloat16*)(ws + HH_OFF);
  unsigned* hh_u = (unsigned*)(ws + HH_OFF);
  unsigned long long* hh_q = (unsigned long long*)(ws + HH_OFF);
  unsigned long long* xc_q = (unsigned long long*)(ws + XC_OFF);
  float* fe = (float*)(ws + FE_OFF);
  unsigned* feu = (unsigned*)(ws + FE_OFF);
  float* lse = (float*)(ws + LSE_OFF);
  int* ctr = (int*)(ws + CTR_OFF);   // ctr[0]=xready ctr[32]=lstmdone ctr[64]=featsdone ctr[96]=lsedone

  // ---- phase 0a: weights -> registers (wave = gate wv, lane = (quad,n16)) --
  const float* Wih = dir ? Wih_b : Wih_f;
  const float* Whh = dir ? Whh_b : Whh_f;
  bf16x8_t bfr[KC_TOT];
  {
    const int j = wv * H_ + nt * 16 + l16;   // original gate row
    const int kq = quad * 8;
    for (int kc = 0; kc < KC_TOT; kc++) {
      int k0 = kc * 32 + kq;
      __hip_bfloat16 v[8];
      #pragma unroll
      for (int jj = 0; jj < 8; jj++) {
        int k = k0 + jj;
        float f;
        if (k < E_) f = Wih[(size_t)j * E_ + k];
        else if (k < KPADX) f = 0.f;
        else f = Whh[(size_t)j * H_ + (k - KPADX)];
        v[jj] = __float2bfloat16(f);
      }
      bfr[kc] = *(bf16x8_t*)v;
    }
  }
  // per-thread (batch, h) assignment for the cell update
  const int bo = tid >> 4, hl = tid & 15;
  const int b = mt * 16 + bo, hg = nt * 16 + hl;
  float c = c0[(size_t)(dir * B_ + b) * H_ + hg];
  const float* bias = dir ? b_b : b_f;
  const float bi_i = bias[hg], bi_f = bias[H_ + hg];
  const float bi_g = bias[2 * H_ + hg], bi_o = bias[3 * H_ + hg];

  // ---- phase 0b: xc slices s=2*bid,2*bid+1 (sc1 stores) + own h0 piece ----
  for (int ss = bid * 2; ss < bid * 2 + 2; ss++) {
    for (int i = tid; i < B_ * 40; i += 256) {
      int bb = i / 40, c8 = i % 40, k0 = c8 * 8;
      const float* src = Wemb + (size_t)tokens[(size_t)bb * S_ + ss] * E_;
      __hip_bfloat16 v[8];
      if (k0 + 8 <= E_) {
        float4 f0 = *(const float4*)(src + k0);
        float4 f1 = *(const float4*)(src + k0 + 4);
        v[0] = __float2bfloat16(f0.x); v[1] = __float2bfloat16(f0.y);
        v[2] = __float2bfloat16(f0.z); v[3] = __float2bfloat16(f0.w);
        v[4] = __float2bfloat16(f1.x); v[5] = __float2bfloat16(f1.y);
        v[6] = __float2bfloat16(f1.z); v[7] = __float2bfloat16(f1.w);
      } else {
        #pragma unroll
        for (int jj = 0; jj < 8; jj++) {
          int k = k0 + jj;
          v[jj] = __float2bfloat16(k < E_ ? src[k] : 0.f);
        }
      }
      unsigned long long* pv = (unsigned long long*)v;
      size_t qo = ((size_t)ss * B_ + bb) * (KPADX / 4) + c8 * 2;
      AGENT_ST(&xc_q[qo], pv[0]);
      AGENT_ST(&xc_q[qo + 1], pv[1]);
    }
  }
  {
    float hv0 = h0[(size_t)(dir * B_ + b) * H_ + hg];
    float hn0 = __shfl_xor(hv0, 1, 64);
    if ((hl & 1) == 0) {
      unsigned short ulo = __builtin_bit_cast(unsigned short, __float2bfloat16(hv0));
      unsigned short uhi = __builtin_bit_cast(unsigned short, __float2bfloat16(hn0));
      unsigned pk = ((unsigned)uhi << 16) | (unsigned)ulo;
      size_t uidx = (((size_t)(dir * (S_ + 1)) * B_ + b) * H_ + hg) >> 1;
      AGENT_ST(&hh_u[uidx], pk);
    }
  }
  // ---- rendezvous 1: xc + h0 globally visible ----
  asm volatile("s_waitcnt vmcnt(0)" ::: "memory");
  __syncthreads();
  if (tid == 0) {
    AGENT_ADD(&ctr[0]);
    while (AGENT_LD(&ctr[0]) < 256) __builtin_amdgcn_s_sleep(2);
  }
  __syncthreads();

  // ---- stage x(0) into pool x-region ----
  {
    int spos0 = dir ? (S_ - 1) : 0;
    for (int i = tid; i < 16 * 40; i += 256) {
      int row = i / 40, c8 = i % 40;
      *(uint4*)(pool + row * ASTR + c8 * 8) =
          *(const uint4*)(xc + ((size_t)spos0 * B_ + mt * 16 + row) * KPADX + c8 * 8);
    }
  }
  __syncthreads();

  // ---- phase 1: LSTM recurrence ----
  const int c2 = tid & 127, r0 = tid >> 7;   // h poll map: rows r0+2k, 8B col c2
  for (int s = 0; s < S_; s++) {
    // issue h(s) poll loads (sc1)
    const size_t qbase = ((size_t)(dir * (S_ + 1) + s) * B_ + mt * 16) * (H_ / 4);
    unsigned long long hv[8];
    #pragma unroll
    for (int k = 0; k < 8; k++)
      hv[k] = AGENT_LD(&hh_q[qbase + (size_t)(r0 + 2 * k) * (H_ / 4) + c2]);
    // issue x(s+1) loads into registers (plain; xc final since rendezvous 1)
    uint4 xv0, xv1, xv2;
    const bool havex = (s + 1 < S_);
    if (havex) {
      int sposn = dir ? (S_ - 2 - s) : (s + 1);
      const __hip_bfloat16* xb = xc + ((size_t)sposn * B_ + mt * 16) * KPADX;
      { int i = tid;       xv0 = *(const uint4*)(xb + (i / 40) * KPADX + (i % 40) * 8); }
      { int i = tid + 256; xv1 = *(const uint4*)(xb + (i / 40) * KPADX + (i % 40) * 8); }
      if (tid < 128) { int i = tid + 512; xv2 = *(const uint4*)(xb + (i / 40) * KPADX + (i % 40) * 8); }
    }
    // x-part MFMAs (kc 0..9) on x(s) already staged — hides the poll RT
    f32x4_t acc0 = (f32x4_t)(0.f), acc1 = (f32x4_t)(0.f);
    #pragma unroll
    for (int kc = 0; kc < 10; kc++) {
      bf16x8_t af = *(const bf16x8_t*)(pool + l16 * ASTR + kc * 32 + quad * 8);
      if (kc < 5) acc0 = __builtin_amdgcn_mfma_f32_16x16x32_bf16(af, bfr[kc], acc0, 0, 0, 0);
      else        acc1 = __builtin_amdgcn_mfma_f32_16x16x32_bf16(af, bfr[kc], acc1, 0, 0, 0);
    }
    // poll until no dword is sentinel (values are write-once)
    for (;;) {
      bool ok = true;
      #pragma unroll
      for (int k = 0; k < 8; k++)
        ok = ok && ((unsigned)hv[k] != SENT) && ((unsigned)(hv[k] >> 32) != SENT);
      if (ok) break;
      #pragma unroll
      for (int k = 0; k < 8; k++)
        hv[k] = AGENT_LD(&hh_q[qbase + (size_t)(r0 + 2 * k) * (H_ / 4) + c2]);
    }
    // stage h(s) into pool h-region
    #pragma unroll
    for (int k = 0; k < 8; k++)
      *(unsigned long long*)(pool + (r0 + 2 * k) * ASTR + KPADX + c2 * 4) = hv[k];
    __syncthreads();                       // sync A
    // h-part MFMAs (kc 10..25), two independent chains
    #pragma unroll
    for (int kc = 10; kc < KC_TOT; kc++) {
      bf16x8_t af = *(const bf16x8_t*)(pool + l16 * ASTR + kc * 32 + quad * 8);
      if (kc < 18) acc0 = __builtin_amdgcn_mfma_f32_16x16x32_bf16(af, bfr[kc], acc0, 0, 0, 0);
      else         acc1 = __builtin_amdgcn_mfma_f32_16x16x32_bf16(af, bfr[kc], acc1, 0, 0, 0);
    }
    f32x4_t accs = acc0 + acc1;
    // gate exchange (each wave writes its own region; no sync needed to write)
    #pragma unroll
    for (int r = 0; r < 4; r++)
      gl[(wv * 16 + quad * 4 + r) * 17 + l16] = accs[r];
    // x(s+1) registers -> pool x-region (loads issued long ago)
    if (havex) {
      { int i = tid;       *(uint4*)(pool + (i / 40) * ASTR + (i % 40) * 8) = xv0; }
      { int i = tid + 256; *(uint4*)(pool + (i / 40) * ASTR + (i % 40) * 8) = xv1; }
      if (tid < 128) { int i = tid + 512; *(uint4*)(pool + (i / 40) * ASTR + (i % 40) * 8) = xv2; }
    }
    __syncthreads();                       // sync B
    // elementwise cell update (c in register)
    float gi = gl[(0 * 16 + bo) * 17 + hl] + bi_i;
    float gf = gl[(1 * 16 + bo) * 17 + hl] + bi_f;
    float gg = gl[(2 * 16 + bo) * 17 + hl] + bi_g;
    float go = gl[(3 * 16 + bo) * 17 + hl] + bi_o;
    float ii = 1.f / (1.f + __expf(-gi));
    float ff = 1.f / (1.f + __expf(-gf));
    float gt = 1.f - 2.f / (1.f + __expf(2.f * gg));   // tanh
    float oo = 1.f / (1.f + __expf(-go));
    c = ff * c + ii * gt;
    float hvv = oo * (1.f - 2.f / (1.f + __expf(2.f * c)));
    // h store: pack 2 bf16 -> sc1 dword; fire-and-forget
    float hn = __shfl_xor(hvv, 1, 64);
    if ((hl & 1) == 0) {
      unsigned short ulo = __builtin_bit_cast(unsigned short, __float2bfloat16(hvv));
      unsigned short uhi = __builtin_bit_cast(unsigned short, __float2bfloat16(hn));
      unsigned pk = ((unsigned)uhi << 16) | (unsigned)ulo;
      size_t uidx = (((size_t)(dir * (S_ + 1) + s + 1) * B_ + b) * H_ + hg) >> 1;
      AGENT_ST(&hh_u[uidx], pk);
    }
  }

  // ---- rendezvous 2: all h final & visible -> plain loads of hh are safe ----
  asm volatile("s_waitcnt vmcnt(0)" ::: "memory");
  __syncthreads();
  if (tid == 0) {
    AGENT_ADD(&ctr[32]);
    while (AGENT_LD(&ctr[32]) < 256) __builtin_amdgcn_s_sleep(2);
  }
  __syncthreads();

  // ---- phase 2: feats for s = 2*bid, 2*bid+1 ----
  for (int i = tid; i < 3072; i += 256) {        // Wout -> LDS, stride 1032
    int r = i >> 8, cc = i & 255;
    *(uint4*)(wl + r * 1032 + cc * 4) = *(const uint4*)(Wout + r * 1024 + cc * 4);
  }
  __syncthreads();
  {
    const int fb = tid >> 2, tg = tid & 3, t0 = tg * 3;
    const float bo0 = bout[t0], bo1 = bout[t0 + 1], bo2 = bout[t0 + 2];
    for (int ss = bid * 2; ss < bid * 2 + 2; ss++) {
      const __hip_bfloat16* hf = hh + ((size_t)(ss + 1) * B_ + fb) * H_;
      const __hip_bfloat16* hb = hh + ((size_t)(S_ + 1 + S_ - ss) * B_ + fb) * H_;
      float a0 = 0.f, a1 = 0.f, a2 = 0.f;
      for (int half = 0; half < 2; half++) {
        const __hip_bfloat16* hp = half ? hb : hf;
        int wof = half * 512;
        for (int k = 0; k < 512; k += 8) {
          uint4 raw = *(const uint4*)(hp + k);
          const __hip_bfloat16* hvp = (const __hip_bfloat16*)&raw;
          float hfl[8];
          #pragma unroll
          for (int j = 0; j < 8; j++) hfl[j] = __bfloat162float(hvp[j]);
          #pragma unroll
          for (int j = 0; j < 8; j++) {
            a0 += hfl[j] * wl[(t0 + 0) * 1032 + wof + k + j];
            a1 += hfl[j] * wl[(t0 + 1) * 1032 + wof + k + j];
            a2 += hfl[j] * wl[(t0 + 2) * 1032 + wof + k + j];
          }
        }
      }
      size_t o = ((size_t)fb * S_ + ss) * T_ + t0;
      AGENT_ST(&feu[o + 0], __builtin_bit_cast(unsigned, a0 + bo0));
      AGENT_ST(&feu[o + 1], __builtin_bit_cast(unsigned, a1 + bo1));
      AGENT_ST(&feu[o + 2], __builtin_bit_cast(unsigned, a2 + bo2));
    }
  }
  // ---- rendezvous 3 arrival (no block-wide wait; only CRF waves wait) ----
  asm volatile("s_waitcnt vmcnt(0)" ::: "memory");
  __syncthreads();
  if (tid == 0) AGENT_ADD(&ctr[64]);
  if (bid >= B_) return;        // blocks 64..255 done
  if (wv != 0) return;          // CRF runs on wave 0 only; no syncthreads below

  // ---- phase 3: CRF forward scan, b = bid ----
  while (AGENT_LD(&ctr[64]) < 256) __builtin_amdgcn_s_sleep(2);
  {
    const float* fbp = fe + (size_t)bid * S_ * T_;
    float tr[12];
    #pragma unroll
    for (int p = 0; p < 12; p++) tr[p] = (lane < 12) ? trans[lane * 12 + p] : 0.f;
    float tstop = (lane < 12) ? trans[11 * 12 + lane] : 0.f;
    float alpha = (lane == 10) ? 0.f : NEGV;
    const int len = lengths[bid];
    float feat = (lane < 12) ? fbp[lane] : 0.f;
    for (int s = 0; s < S_; s++) {
      float fn = (lane < 12 && s + 1 < S_) ? fbp[(size_t)(s + 1) * T_ + lane] : 0.f;
      float av[12];
      #pragma unroll
      for (int p = 0; p < 12; p++) av[p] = __shfl(alpha, p, 64) + tr[p];
      float mx = av[0];
      #pragma unroll
      for (int p = 1; p < 12; p++) mx = fmaxf(mx, av[p]);
      float sum = 0.f;
      #pragma unroll
      for (int p = 0; p < 12; p++) sum += __expf(av[p] - mx);
      float nw = mx + __logf(sum) + feat;
      if (s < len && lane < 12) alpha = nw;
      feat = fn;
    }
    float tv = (lane < 12) ? (alpha + tstop) : -3.0e38f;
    float mx = tv;
    #pragma unroll
    for (int off = 32; off > 0; off >>= 1) mx = fmaxf(mx, __shfl_xor(mx, off, 64));
    float sum = __expf(tv - mx);
    #pragma unroll
    for (int off = 32; off > 0; off >>= 1) sum += __shfl_xor(sum, off, 64);
    if (lane == 0)
      AGENT_ST((unsigned*)&lse[bid], __builtin_bit_cast(unsigned, mx + __logf(sum)));
  }
  asm volatile("s_waitcnt vmcnt(0)" ::: "memory");
  if (lane == 0) AGENT_ADD(&ctr[96]);
  if (bid != 0) return;

  // ---- phase 4: final mean (block 0, wave 0) ----
  while (AGENT_LD(&ctr[96]) < B_) __builtin_amdgcn_s_sleep(2);
  {
    float v = __builtin_bit_cast(float, AGENT_LD((unsigned*)&lse[lane]));
    #pragma unroll
    for (int off = 32; off > 0; off >>= 1) v += __shfl_xor(v, off, 64);
    if (lane == 0) out[0] = v * (1.f / 64.f);
  }
}

// ---------------------------------------------------------------------------
extern "C" void kernel_launch(void* const* d_in, const int* in_sizes, int n_in,
                              void* d_out, int out_size, void* d_ws, size_t ws_size,
                              hipStream_t stream) {
  (void)in_sizes; (void)n_in; (void)out_size; (void)ws_size;
  const int* tokens = (const int*)d_in[0];
  const int* lengths = (const int*)d_in[1];
  const float* Wemb = (const float*)d_in[2];
  const float* Wih_f = (const float*)d_in[3];
  const float* Whh_f = (const float*)d_in[4];
  const float* b_f = (const float*)d_in[5];
  const float* Wih_b = (const float*)d_in[6];
  const float* Whh_b = (const float*)d_in[7];
  const float* b_b = (const float*)d_in[8];
  const float* h0 = (const float*)d_in[9];
  const float* c0 = (const float*)d_in[10];
  const float* Wout = (const float*)d_in[11];
  const float* bout = (const float*)d_in[12];
  const float* trans = (const float*)d_in[13];
  char* ws = (char*)d_ws;
  float* out = (float*)d_out;

  // sentinel-fill h history; zero the rendezvous counters
  hipMemsetAsync(ws + HH_OFF, 0xFF, HH_BYTES, stream);
  hipMemsetAsync(ws + CTR_OFF, 0, CTR_BYTES, stream);
  hipLaunchKernelGGL(bilstm_crf_persist, dim3(256), dim3(256), 0, stream,
                     tokens, lengths, Wemb, Wih_f, Whh_f, b_f,
                     Wih_b, Whh_b, b_b, h0, c0, Wout, bout, trans, ws, out);
}